// Round 15
// baseline (567.290 us; speedup 1.0000x reference)
//
#include <hip/hip_runtime.h>
#include <hip/hip_fp16.h>

#define IN_F 24
#define HID 64
#define NB 512      // dst buckets (node ranges)
#define NPB 256     // partition blocks (edge slices)
#define GSZ_MAX 256 // max nodes per bucket (ceil(100000/512) = 196)
#define SRC_BITS 17 // src < 100000 < 2^17; loc < 196 < 2^8
#define SRC_MASK ((1u << SRC_BITS) - 1)

typedef unsigned int u32;

// bucket of node d:  k = floor(d*NB/n)
// node range of bucket b (exact inverse):  [ceil(b*n/NB), ceil((b+1)*n/NB))
__device__ __forceinline__ int bucket_lo(int b, int n) {
    return (int)(((long long)b * n + NB - 1) / NB);
}

// ---------------- pass 1a: per-(slice,bucket) histogram ----------------
__global__ __launch_bounds__(256) void k_pcount(const int* __restrict__ dst,
                                                u32* __restrict__ pc, int e, int n) {
    __shared__ u32 h[NB];
    for (int j = threadIdx.x; j < NB; j += 256) h[j] = 0;
    __syncthreads();
    int blk = blockIdx.x;
    long long begin = (long long)e * blk / NPB;
    long long end   = (long long)e * (blk + 1) / NPB;
    for (long long i = begin + threadIdx.x; i < end; i += 256) {
        int k = (int)((long long)dst[i] * NB / n);
        atomicAdd(&h[k], 1u);
    }
    __syncthreads();
    for (int j = threadIdx.x; j < NB; j += 256) pc[(size_t)blk * NB + j] = h[j];
}

// ---------------- pass 1b-parallel: per-column exclusive scan (NPB=256 rows) ----------------
__global__ __launch_bounds__(256) void k_pscan_a(u32* __restrict__ pc,
                                                 u32* __restrict__ colsum) {
    __shared__ u32 ps[256];
    int t = blockIdx.x;   // column (bucket)
    int tid = threadIdx.x;
    u32 v = pc[(size_t)tid * NB + t];
    ps[tid] = v;
    __syncthreads();
    for (int off = 1; off < 256; off <<= 1) {
        u32 v2 = (tid >= off) ? ps[tid - off] : 0;
        __syncthreads();
        ps[tid] += v2;
        __syncthreads();
    }
    pc[(size_t)tid * NB + t] = ps[tid] - v;   // exclusive within-column
    if (tid == 255) colsum[t] = ps[255];
}

// exclusive scan of the 512 column sums -> bucket bases
__global__ void k_pscan_b(const u32* __restrict__ colsum, u32* __restrict__ basep) {
    __shared__ u32 s[NB];
    int t = threadIdx.x;
    u32 v = colsum[t];
    s[t] = v;
    __syncthreads();
    for (int off = 1; off < NB; off <<= 1) {
        u32 v2 = (t >= off) ? s[t - off] : 0;
        __syncthreads();
        s[t] += v2;
        __syncthreads();
    }
    basep[t] = s[t] - v;
}

// ---------------- pass 1c: direct scatter of packed (loc<<17|src) into bucket order ----------------
// (R12 version — measured best; staged-LDS variants regressed: R13 53us, R14 62us vs this 51us)
__global__ __launch_bounds__(256) void k_part(const int* __restrict__ src,
                                              const int* __restrict__ dst,
                                              const u32* __restrict__ pc,
                                              const u32* __restrict__ basep,
                                              u32* __restrict__ pairs, int e, int n) {
    __shared__ u32 cur[NB];
    int blk = (blockIdx.x & 7) * (NPB / 8) + (blockIdx.x >> 3);  // XCD-affine (perf heuristic)
    for (int j = threadIdx.x; j < NB; j += 256)
        cur[j] = pc[(size_t)blk * NB + j] + basep[j];
    __syncthreads();
    long long begin = (long long)e * blk / NPB;
    long long end   = (long long)e * (blk + 1) / NPB;
    for (long long i = begin + threadIdx.x; i < end; i += 256) {
        int d = dst[i];
        int sv = src[i];
        int k = (int)((long long)d * NB / n);
        u32 loc = (u32)(d - bucket_lo(k, n));
        u32 pos = atomicAdd(&cur[k], 1u);
        pairs[pos] = (loc << SRC_BITS) | (u32)sv;
    }
}

// ---------------- pass 2a: per-bucket degree count -> dinv + fused xs f16 pack ----------------
__global__ __launch_bounds__(256) void k_count_pack(const u32* __restrict__ pairs,
                                                    const u32* __restrict__ basep,
                                                    const float* __restrict__ x,
                                                    float* __restrict__ dinv,
                                                    __half2* __restrict__ xs2, int e, int n) {
    __shared__ u32 h[GSZ_MAX];
    __shared__ float dloc[GSZ_MAX];
    int b = blockIdx.x;
    int lo = bucket_lo(b, n);
    int hi = bucket_lo(b + 1, n);
    int gsz = hi - lo;
    u32 start = basep[b];
    u32 endp = (b + 1 < NB) ? basep[b + 1] : (u32)e;
    for (int j = threadIdx.x; j < GSZ_MAX; j += 256) h[j] = 0;
    __syncthreads();
    for (u32 i = start + threadIdx.x; i < endp; i += 256)
        atomicAdd(&h[pairs[i] >> SRC_BITS], 1u);
    __syncthreads();
    int t = threadIdx.x;
    if (t < gsz) {
        float dv = rsqrtf((float)(h[t] + 1));  // +1 self-loop
        dinv[lo + t] = dv;
        dloc[t] = dv;
    }
    __syncthreads();
    // pack: xs[i][f] = f16(x[i][f] * dinv[i]) for this bucket's nodes (contiguous)
    const float2* xf = (const float2*)(x + (long long)lo * IN_F);
    for (int i = threadIdx.x; i < gsz * 12; i += 256) {
        float2 v = xf[i];
        float dn = dloc[i / 12];
        xs2[(long long)lo * 12 + i] = __floats2half2_rn(v.x * dn, v.y * dn);
    }
}

// ---------------- pass 2b: layer-1 aggregation via LDS float atomics ----------------
// 16 groups of 16 lanes; each group takes 8 consecutive pairs per iter -> 64+ outstanding
// gathers per wave. acc rows are 24 consecutive floats -> 24 distinct banks, conflict-free
// within a group.
__global__ __launch_bounds__(256) void k_agg_pairs(const u32* __restrict__ pairs,
                                                   const u32* __restrict__ basep,
                                                   const __half2* __restrict__ xs2,
                                                   const float* __restrict__ dinv,
                                                   const float* __restrict__ x,
                                                   float* __restrict__ aggX, int e, int n) {
    __shared__ float acc[GSZ_MAX * 24];
    __shared__ float dloc[GSZ_MAX];
    int b = blockIdx.x;
    int lo = bucket_lo(b, n);
    int hi = bucket_lo(b + 1, n);
    int gsz = hi - lo;
    u32 start = basep[b];
    u32 endp = (b + 1 < NB) ? basep[b + 1] : (u32)e;
    int nel = gsz * 24;
    for (int i = threadIdx.x; i < nel; i += 256) acc[i] = 0.0f;
    if (threadIdx.x < gsz) dloc[threadIdx.x] = dinv[lo + threadIdx.x];
    __syncthreads();
    int g = threadIdx.x >> 4;
    int f2 = threadIdx.x & 15;
    u32 cnt2 = endp - start;
    u32 nfull = cnt2 & ~127u;   // multiple of 128 (16 groups x 8)
    for (u32 base2 = start; base2 < start + nfull; base2 += 128) {
        u32 i0 = base2 + g * 8;
        u32 p0 = pairs[i0],     p1 = pairs[i0 + 1], p2 = pairs[i0 + 2], p3 = pairs[i0 + 3];
        u32 p4 = pairs[i0 + 4], p5 = pairs[i0 + 5], p6 = pairs[i0 + 6], p7 = pairs[i0 + 7];
        if (f2 < 12) {
            __half2 a0 = xs2[(p0 & SRC_MASK) * 12 + f2];
            __half2 a1 = xs2[(p1 & SRC_MASK) * 12 + f2];
            __half2 a2 = xs2[(p2 & SRC_MASK) * 12 + f2];
            __half2 a3 = xs2[(p3 & SRC_MASK) * 12 + f2];
            __half2 a4 = xs2[(p4 & SRC_MASK) * 12 + f2];
            __half2 a5 = xs2[(p5 & SRC_MASK) * 12 + f2];
            __half2 a6 = xs2[(p6 & SRC_MASK) * 12 + f2];
            __half2 a7 = xs2[(p7 & SRC_MASK) * 12 + f2];
            float2 v;
            v = __half22float2(a0);
            atomicAdd(&acc[(p0 >> SRC_BITS) * 24 + 2 * f2], v.x);
            atomicAdd(&acc[(p0 >> SRC_BITS) * 24 + 2 * f2 + 1], v.y);
            v = __half22float2(a1);
            atomicAdd(&acc[(p1 >> SRC_BITS) * 24 + 2 * f2], v.x);
            atomicAdd(&acc[(p1 >> SRC_BITS) * 24 + 2 * f2 + 1], v.y);
            v = __half22float2(a2);
            atomicAdd(&acc[(p2 >> SRC_BITS) * 24 + 2 * f2], v.x);
            atomicAdd(&acc[(p2 >> SRC_BITS) * 24 + 2 * f2 + 1], v.y);
            v = __half22float2(a3);
            atomicAdd(&acc[(p3 >> SRC_BITS) * 24 + 2 * f2], v.x);
            atomicAdd(&acc[(p3 >> SRC_BITS) * 24 + 2 * f2 + 1], v.y);
            v = __half22float2(a4);
            atomicAdd(&acc[(p4 >> SRC_BITS) * 24 + 2 * f2], v.x);
            atomicAdd(&acc[(p4 >> SRC_BITS) * 24 + 2 * f2 + 1], v.y);
            v = __half22float2(a5);
            atomicAdd(&acc[(p5 >> SRC_BITS) * 24 + 2 * f2], v.x);
            atomicAdd(&acc[(p5 >> SRC_BITS) * 24 + 2 * f2 + 1], v.y);
            v = __half22float2(a6);
            atomicAdd(&acc[(p6 >> SRC_BITS) * 24 + 2 * f2], v.x);
            atomicAdd(&acc[(p6 >> SRC_BITS) * 24 + 2 * f2 + 1], v.y);
            v = __half22float2(a7);
            atomicAdd(&acc[(p7 >> SRC_BITS) * 24 + 2 * f2], v.x);
            atomicAdd(&acc[(p7 >> SRC_BITS) * 24 + 2 * f2 + 1], v.y);
        }
    }
    // tail: one pair per group
    for (u32 i = start + nfull + g; i < endp; i += 16) {
        u32 p = pairs[i];
        if (f2 < 12) {
            float2 v = __half22float2(xs2[(p & SRC_MASK) * 12 + f2]);
            atomicAdd(&acc[(p >> SRC_BITS) * 24 + 2 * f2], v.x);
            atomicAdd(&acc[(p >> SRC_BITS) * 24 + 2 * f2 + 1], v.y);
        }
    }
    __syncthreads();
    // epilogue: aggX = (acc + x_self*dinv) * dinv  (contiguous read/write)
    const float* xr = x + (long long)lo * IN_F;
    float* ar = aggX + (long long)lo * IN_F;
    for (int i = threadIdx.x; i < nel; i += 256) {
        float dn = dloc[i / 24];
        ar[i] = (acc[i] + xr[i] * dn) * dn;
    }
}

// ---------------- fused layer-1 transform + layer-2 lin: one thread per node ----------------
__global__ __launch_bounds__(256) void k_hidden_z(const float* __restrict__ aggX,
                                                  const float* __restrict__ W1,
                                                  const float* __restrict__ b1,
                                                  const float* __restrict__ W2,
                                                  const float* __restrict__ dinv,
                                                  float* __restrict__ zs, int n) {
    __shared__ float w[IN_F * HID];   // k-major: w[k*64+f]
    __shared__ float w2s[HID];
    __shared__ float b1s[HID];
    for (int j = threadIdx.x; j < IN_F * HID; j += 256) w[j] = W1[j];
    if (threadIdx.x < HID) { w2s[threadIdx.x] = W2[threadIdx.x]; b1s[threadIdx.x] = b1[threadIdx.x]; }
    __syncthreads();
    int node = blockIdx.x * 256 + threadIdx.x;
    if (node >= n) return;
    float h[HID];
#pragma unroll
    for (int f = 0; f < HID; ++f) h[f] = b1s[f];
    const float4* xp = (const float4*)(aggX + (long long)node * IN_F);
#pragma unroll
    for (int kk = 0; kk < IN_F / 4; ++kk) {
        float4 xv = xp[kk];
        const float* w0 = w + (kk * 4) * HID;
#pragma unroll
        for (int f = 0; f < HID; ++f) h[f] += xv.x * w0[f];
        const float* w1r = w0 + HID;
#pragma unroll
        for (int f = 0; f < HID; ++f) h[f] += xv.y * w1r[f];
        const float* w2r = w1r + HID;
#pragma unroll
        for (int f = 0; f < HID; ++f) h[f] += xv.z * w2r[f];
        const float* w3r = w2r + HID;
#pragma unroll
        for (int f = 0; f < HID; ++f) h[f] += xv.w * w3r[f];
    }
    float acc = 0.0f;
#pragma unroll
    for (int f = 0; f < HID; ++f) acc += fmaxf(h[f], 0.0f) * w2s[f];
    zs[node] = acc * dinv[node];
}

// ---------------- layer 2: stream pairs, LDS-atomic scalar accumulate ----------------
__global__ __launch_bounds__(256) void k_out_pairs(const u32* __restrict__ pairs,
                                                   const u32* __restrict__ basep,
                                                   const float* __restrict__ zs,
                                                   const float* __restrict__ dinv,
                                                   const float* __restrict__ b2,
                                                   float* __restrict__ out, int e, int n) {
    __shared__ float accz[GSZ_MAX];
    int b = blockIdx.x;
    int lo = bucket_lo(b, n);
    int hi = bucket_lo(b + 1, n);
    int gsz = hi - lo;
    u32 start = basep[b];
    u32 endp = (b + 1 < NB) ? basep[b + 1] : (u32)e;
    for (int j = threadIdx.x; j < GSZ_MAX; j += 256) accz[j] = 0.0f;
    __syncthreads();
    u32 cnt2 = endp - start;
    u32 nfull = cnt2 & ~3u;
    for (u32 i = start + threadIdx.x * 4; i < start + nfull; i += 1024) {
        u32 p0 = pairs[i], p1 = pairs[i + 1], p2 = pairs[i + 2], p3 = pairs[i + 3];
        float z0 = zs[p0 & SRC_MASK];
        float z1 = zs[p1 & SRC_MASK];
        float z2 = zs[p2 & SRC_MASK];
        float z3 = zs[p3 & SRC_MASK];
        atomicAdd(&accz[p0 >> SRC_BITS], z0);
        atomicAdd(&accz[p1 >> SRC_BITS], z1);
        atomicAdd(&accz[p2 >> SRC_BITS], z2);
        atomicAdd(&accz[p3 >> SRC_BITS], z3);
    }
    for (u32 i = start + nfull + threadIdx.x; i < endp; i += 256) {
        u32 p = pairs[i];
        atomicAdd(&accz[p >> SRC_BITS], zs[p & SRC_MASK]);
    }
    __syncthreads();
    int t = threadIdx.x;
    if (t < gsz) {
        out[lo + t] = b2[0] + dinv[lo + t] * (zs[lo + t] + accz[t]);
    }
}

extern "C" void kernel_launch(void* const* d_in, const int* in_sizes, int n_in,
                              void* d_out, int out_size, void* d_ws, size_t ws_size,
                              hipStream_t stream) {
    const float* x   = (const float*)d_in[0];
    const int*   ei  = (const int*)d_in[1];
    const float* W1  = (const float*)d_in[2];
    const float* b1  = (const float*)d_in[3];
    const float* W2  = (const float*)d_in[4];
    const float* b2  = (const float*)d_in[5];
    float* out = (float*)d_out;

    const int n = in_sizes[0] / IN_F;      // 100000
    const int e = in_sizes[1] / 2;         // 3200000
    const int* src = ei;
    const int* dst = ei + e;

    const int B = 256;

    // workspace layout — no overlays (pairs live to the end). ~28.5 MB total.
    char* base = (char*)d_ws;
    u32* pairs  = (u32*)base;                           // e u32 (12.8 MB)
    float* dinv = (float*)(pairs + e);                  // n f32
    __half* xs  = (__half*)(dinv + n);                  // n*24 f16 (4.8 MB)
    float* aggX = (float*)(xs + (size_t)n * IN_F);      // n*24 f32 (9.6 MB)
    float* zs   = aggX + (size_t)n * IN_F;              // n f32
    u32* pc     = (u32*)(zs + n);                       // NPB*NB u32 (0.5 MB)
    u32* colsum = pc + (size_t)NPB * NB;                // NB u32
    u32* basep  = colsum + NB;                          // NB u32

    // bucket sort of (loc,src) pairs by dst bucket (no device-scope atomics)
    k_pcount<<<NPB, B, 0, stream>>>(dst, pc, e, n);
    k_pscan_a<<<NB, B, 0, stream>>>(pc, colsum);
    k_pscan_b<<<1, NB, 0, stream>>>(colsum, basep);
    k_part<<<NPB, B, 0, stream>>>(src, dst, pc, basep, pairs, e, n);

    // degree -> dinv + f16 pack (per bucket)
    k_count_pack<<<NB, B, 0, stream>>>(pairs, basep, x, dinv, (__half2*)xs, e, n);

    // layer 1 aggregation (LDS-atomic accumulate per bucket), then dense transform
    k_agg_pairs<<<NB, B, 0, stream>>>(pairs, basep, (const __half2*)xs, dinv, x, aggX, e, n);
    k_hidden_z<<<(n + B - 1) / B, B, 0, stream>>>(aggX, W1, b1, W2, dinv, zs, n);

    // layer 2 aggregation + output (per bucket)
    k_out_pairs<<<NB, B, 0, stream>>>(pairs, basep, zs, dinv, b2, out, e, n);
}

// Round 16
// 227.007 us; speedup vs baseline: 2.4990x; 2.4990x over previous
//
#include <hip/hip_runtime.h>
#include <hip/hip_fp16.h>

#define IN_F 24
#define HID 64
#define NB 512      // dst buckets (node ranges)
#define NPB 256     // partition blocks (edge slices)
#define GSZ_MAX 256 // max nodes per bucket (ceil(100000/512) = 196)
#define PBUF 7168   // pair capacity per bucket in LDS (mean ~6250, +11 sigma)
#define SRC_BITS 17 // src < 100000 < 2^17; loc < 196 < 2^8

typedef unsigned int u32;

// bucket of node d:  k = floor(d*NB/n)
// node range of bucket b (exact inverse):  [ceil(b*n/NB), ceil((b+1)*n/NB))
__device__ __forceinline__ int bucket_lo(int b, int n) {
    return (int)(((long long)b * n + NB - 1) / NB);
}

// ---------------- pass 1a: per-(slice,bucket) histogram ----------------
__global__ __launch_bounds__(256) void k_pcount(const int* __restrict__ dst,
                                                u32* __restrict__ pc, int e, int n) {
    __shared__ u32 h[NB];
    for (int j = threadIdx.x; j < NB; j += 256) h[j] = 0;
    __syncthreads();
    int blk = blockIdx.x;
    long long begin = (long long)e * blk / NPB;
    long long end   = (long long)e * (blk + 1) / NPB;
    for (long long i = begin + threadIdx.x; i < end; i += 256) {
        int k = (int)((long long)dst[i] * NB / n);
        atomicAdd(&h[k], 1u);
    }
    __syncthreads();
    for (int j = threadIdx.x; j < NB; j += 256) pc[(size_t)blk * NB + j] = h[j];
}

// ---------------- pass 1b-parallel: per-column exclusive scan (NPB=256 rows) ----------------
__global__ __launch_bounds__(256) void k_pscan_a(u32* __restrict__ pc,
                                                 u32* __restrict__ colsum) {
    __shared__ u32 ps[256];
    int t = blockIdx.x;   // column (bucket)
    int tid = threadIdx.x;
    u32 v = pc[(size_t)tid * NB + t];
    ps[tid] = v;
    __syncthreads();
    for (int off = 1; off < 256; off <<= 1) {
        u32 v2 = (tid >= off) ? ps[tid - off] : 0;
        __syncthreads();
        ps[tid] += v2;
        __syncthreads();
    }
    pc[(size_t)tid * NB + t] = ps[tid] - v;   // exclusive within-column
    if (tid == 255) colsum[t] = ps[255];
}

// exclusive scan of the 512 column sums -> bucket bases
__global__ void k_pscan_b(const u32* __restrict__ colsum, u32* __restrict__ basep) {
    __shared__ u32 s[NB];
    int t = threadIdx.x;
    u32 v = colsum[t];
    s[t] = v;
    __syncthreads();
    for (int off = 1; off < NB; off <<= 1) {
        u32 v2 = (t >= off) ? s[t - off] : 0;
        __syncthreads();
        s[t] += v2;
        __syncthreads();
    }
    basep[t] = s[t] - v;
}

// ---------------- pass 1c: direct scatter of packed (loc<<17|src) into bucket order ----------------
// (measured best; staged-LDS variants regressed: R13 53us, R14 62us, vs this <=43us)
__global__ __launch_bounds__(256) void k_part(const int* __restrict__ src,
                                              const int* __restrict__ dst,
                                              const u32* __restrict__ pc,
                                              const u32* __restrict__ basep,
                                              u32* __restrict__ pairs, int e, int n) {
    __shared__ u32 cur[NB];
    int blk = (blockIdx.x & 7) * (NPB / 8) + (blockIdx.x >> 3);  // XCD-affine (perf heuristic)
    for (int j = threadIdx.x; j < NB; j += 256)
        cur[j] = pc[(size_t)blk * NB + j] + basep[j];
    __syncthreads();
    long long begin = (long long)e * blk / NPB;
    long long end   = (long long)e * (blk + 1) / NPB;
    for (long long i = begin + threadIdx.x; i < end; i += 256) {
        int d = dst[i];
        int sv = src[i];
        int k = (int)((long long)d * NB / n);
        u32 loc = (u32)(d - bucket_lo(k, n));
        u32 pos = atomicAdd(&cur[k], 1u);
        pairs[pos] = (loc << SRC_BITS) | (u32)sv;
    }
}

// ---------------- pass 2: per-bucket mini-CSR in LDS (+ fused xs f16 pack) ----------------
__global__ __launch_bounds__(256) void k_bucket(const u32* __restrict__ pairs,
                                                const u32* __restrict__ basep,
                                                const float* __restrict__ x,
                                                int* __restrict__ cnt,
                                                int* __restrict__ row_start,
                                                float* __restrict__ dinv,
                                                int* __restrict__ csr_src,
                                                __half2* __restrict__ xs2, int e, int n) {
    __shared__ u32 pbuf[PBUF];
    __shared__ u32 h[GSZ_MAX];
    __shared__ u32 cur[GSZ_MAX];
    __shared__ u32 sc[GSZ_MAX];
    __shared__ float dloc[GSZ_MAX];
    int b = blockIdx.x;
    int lo = bucket_lo(b, n);
    int hi = bucket_lo(b + 1, n);
    int gsz = hi - lo;               // <= GSZ_MAX
    u32 start = basep[b];
    u32 endp = (b + 1 < NB) ? basep[b + 1] : (u32)e;
    int nbp = (int)(endp - start);
    for (int j = threadIdx.x; j < GSZ_MAX; j += 256) h[j] = 0;
    __syncthreads();
    int stored = nbp < PBUF ? nbp : PBUF;
    for (int i = threadIdx.x; i < stored; i += 256) {
        u32 p = pairs[start + i];
        pbuf[i] = p;
        atomicAdd(&h[p >> SRC_BITS], 1u);
    }
    for (int i = PBUF + threadIdx.x; i < nbp; i += 256) {  // overflow path (rare)
        atomicAdd(&h[pairs[start + i] >> SRC_BITS], 1u);
    }
    __syncthreads();
    int t = threadIdx.x;
    u32 v = h[t];
    sc[t] = v;
    __syncthreads();
    for (int off = 1; off < 256; off <<= 1) {
        u32 v2 = (t >= off) ? sc[t - off] : 0;
        __syncthreads();
        sc[t] += v2;
        __syncthreads();
    }
    u32 excl = sc[t] - v;
    if (t < gsz) {
        float dv = rsqrtf((float)(v + 1));  // +1 self-loop
        cnt[lo + t] = (int)v;
        row_start[lo + t] = (int)(start + excl);
        dinv[lo + t] = dv;
        dloc[t] = dv;
        cur[t] = excl;
    }
    __syncthreads();
    for (int i = threadIdx.x; i < stored; i += 256) {
        u32 p = pbuf[i];
        u32 pos = atomicAdd(&cur[p >> SRC_BITS], 1u);
        csr_src[start + pos] = (int)(p & ((1u << SRC_BITS) - 1));
    }
    for (int i = PBUF + threadIdx.x; i < nbp; i += 256) {
        u32 p = pairs[start + i];
        u32 pos = atomicAdd(&cur[p >> SRC_BITS], 1u);
        csr_src[start + pos] = (int)(p & ((1u << SRC_BITS) - 1));
    }
    // fused pack: xs[i][f] = f16(x[i][f] * dinv[i]) for this bucket's nodes (contiguous)
    const float2* xf = (const float2*)(x + (long long)lo * IN_F);
    for (int i = threadIdx.x; i < gsz * 12; i += 256) {
        float2 vv = xf[i];
        float dn = dloc[i / 12];
        xs2[(long long)lo * 12 + i] = __floats2half2_rn(vv.x * dn, vv.y * dn);
    }
}

// ---------------- layer 1 aggregation: 16-lane group per node, half2 payload, unroll-8 ----------------
__global__ void k_agg1(const float* __restrict__ x, const __half2* __restrict__ xs2,
                       const float* __restrict__ dinv, const int* __restrict__ row_start,
                       const int* __restrict__ cnt, const int* __restrict__ csr_src,
                       float2* __restrict__ aggX2, int n) {
    int t = blockIdx.x * blockDim.x + threadIdx.x;
    int node = t >> 4;
    int f2 = t & 15;
    if (node >= n || f2 >= 12) return;
    int row = row_start[node];
    int c = cnt[node];
    float ax = 0.0f, ay = 0.0f;
    int j = 0;
    for (; j + 8 <= c; j += 8) {
        const int* cp = csr_src + row + j;
        int s0 = cp[0], s1 = cp[1], s2 = cp[2], s3 = cp[3];
        int s4 = cp[4], s5 = cp[5], s6 = cp[6], s7 = cp[7];
        __half2 h0 = xs2[s0 * 12 + f2];
        __half2 h1 = xs2[s1 * 12 + f2];
        __half2 h2 = xs2[s2 * 12 + f2];
        __half2 h3 = xs2[s3 * 12 + f2];
        __half2 h4 = xs2[s4 * 12 + f2];
        __half2 h5 = xs2[s5 * 12 + f2];
        __half2 h6 = xs2[s6 * 12 + f2];
        __half2 h7 = xs2[s7 * 12 + f2];
        float2 f0 = __half22float2(h0), f1 = __half22float2(h1);
        float2 f2v = __half22float2(h2), f3 = __half22float2(h3);
        float2 f4 = __half22float2(h4), f5 = __half22float2(h5);
        float2 f6 = __half22float2(h6), f7 = __half22float2(h7);
        ax += (f0.x + f1.x) + (f2v.x + f3.x) + ((f4.x + f5.x) + (f6.x + f7.x));
        ay += (f0.y + f1.y) + (f2v.y + f3.y) + ((f4.y + f5.y) + (f6.y + f7.y));
    }
    for (; j < c; ++j) {
        int s = csr_src[row + j];
        float2 fv = __half22float2(xs2[s * 12 + f2]);
        ax += fv.x;
        ay += fv.y;
    }
    float dn = dinv[node];
    float sx = x[(long long)node * IN_F + 2 * f2];
    float sy = x[(long long)node * IN_F + 2 * f2 + 1];
    float2 outv;
    outv.x = (ax + sx * dn) * dn;
    outv.y = (ay + sy * dn) * dn;
    aggX2[(long long)node * 12 + f2] = outv;
}

// ---------------- fused layer-1 transform + layer-2 lin: one thread per node ----------------
__global__ __launch_bounds__(256) void k_hidden_z(const float* __restrict__ aggX,
                                                  const float* __restrict__ W1,
                                                  const float* __restrict__ b1,
                                                  const float* __restrict__ W2,
                                                  const float* __restrict__ dinv,
                                                  float* __restrict__ zs, int n) {
    __shared__ float w[IN_F * HID];   // k-major: w[k*64+f]
    __shared__ float w2s[HID];
    __shared__ float b1s[HID];
    for (int j = threadIdx.x; j < IN_F * HID; j += 256) w[j] = W1[j];
    if (threadIdx.x < HID) { w2s[threadIdx.x] = W2[threadIdx.x]; b1s[threadIdx.x] = b1[threadIdx.x]; }
    __syncthreads();
    int node = blockIdx.x * 256 + threadIdx.x;
    if (node >= n) return;
    float h[HID];
#pragma unroll
    for (int f = 0; f < HID; ++f) h[f] = b1s[f];
    const float4* xp = (const float4*)(aggX + (long long)node * IN_F);
#pragma unroll
    for (int kk = 0; kk < IN_F / 4; ++kk) {
        float4 xv = xp[kk];
        const float* w0 = w + (kk * 4) * HID;
#pragma unroll
        for (int f = 0; f < HID; ++f) h[f] += xv.x * w0[f];
        const float* w1r = w0 + HID;
#pragma unroll
        for (int f = 0; f < HID; ++f) h[f] += xv.y * w1r[f];
        const float* w2r = w1r + HID;
#pragma unroll
        for (int f = 0; f < HID; ++f) h[f] += xv.z * w2r[f];
        const float* w3r = w2r + HID;
#pragma unroll
        for (int f = 0; f < HID; ++f) h[f] += xv.w * w3r[f];
    }
    float acc = 0.0f;
#pragma unroll
    for (int f = 0; f < HID; ++f) acc += fmaxf(h[f], 0.0f) * w2s[f];
    zs[node] = acc * dinv[node];
}

// ---------------- layer 2 gather: 16-lane group per node ----------------
__global__ void k_out(const float* __restrict__ zs, const float* __restrict__ dinv,
                      const int* __restrict__ row_start, const int* __restrict__ cnt,
                      const int* __restrict__ csr_src, const float* __restrict__ b2,
                      float* __restrict__ out, int n) {
    int t = blockIdx.x * blockDim.x + threadIdx.x;
    int node = t >> 4;
    int lane = t & 15;
    if (node >= n) return;
    int row = row_start[node];
    int c = cnt[node];
    float v = 0.0f;
    for (int j = lane; j < c; j += 16) {
        v += zs[csr_src[row + j]];
    }
    v += __shfl_down(v, 8, 16);
    v += __shfl_down(v, 4, 16);
    v += __shfl_down(v, 2, 16);
    v += __shfl_down(v, 1, 16);
    if (lane == 0) {
        out[node] = b2[0] + dinv[node] * (zs[node] + v);
    }
}

extern "C" void kernel_launch(void* const* d_in, const int* in_sizes, int n_in,
                              void* d_out, int out_size, void* d_ws, size_t ws_size,
                              hipStream_t stream) {
    const float* x   = (const float*)d_in[0];
    const int*   ei  = (const int*)d_in[1];
    const float* W1  = (const float*)d_in[2];
    const float* b1  = (const float*)d_in[3];
    const float* W2  = (const float*)d_in[4];
    const float* b2  = (const float*)d_in[5];
    float* out = (float*)d_out;

    const int n = in_sizes[0] / IN_F;      // 100000
    const int e = in_sizes[1] / 2;         // 3200000
    const int* src = ei;
    const int* dst = ei + e;

    const int B = 256;

    // workspace layout. pairs (u32, CSR build) overlays aggX/zs ONLY (lifetimes disjoint:
    // pairs dead after k_bucket; aggX/zs born after). xs is written by k_bucket while other
    // blocks still read pairs -> xs placed OUTSIDE the overlay.
    char* base = (char*)d_ws;
    u32* pairs     = (u32*)base;                        // e u32 (12.8 MB)
    float* aggX    = (float*)base;                      // n*24 f32 (9.6 MB)   [overlay]
    float* zs      = aggX + (size_t)n * IN_F;           // n f32              [overlay]
    size_t ov = (size_t)e * 4;
    size_t ov2 = (size_t)n * 100;                       // aggX(96n) + zs(4n)
    if (ov2 > ov) ov = ov2;
    ov = (ov + 255) & ~(size_t)255;
    char* after    = base + ov;
    int* cnt       = (int*)after;
    int* row_start = cnt + n;
    int* csr_src   = row_start + n;                     // e ints (12.8 MB)
    float* dinv    = (float*)(csr_src + e);
    __half* xs     = (__half*)(dinv + n);               // n*24 f16 (4.8 MB) — NOT overlaid
    u32* pc        = (u32*)(xs + (size_t)n * IN_F);     // NPB*NB u32 (0.5 MB)
    u32* colsum    = pc + (size_t)NPB * NB;             // NB u32
    u32* basep     = colsum + NB;                       // NB u32

    // CSR build: single-read two-level bucket sort (no device-scope atomics)
    k_pcount<<<NPB, B, 0, stream>>>(dst, pc, e, n);
    k_pscan_a<<<NB, B, 0, stream>>>(pc, colsum);
    k_pscan_b<<<1, NB, 0, stream>>>(colsum, basep);
    k_part<<<NPB, B, 0, stream>>>(src, dst, pc, basep, pairs, e, n);
    k_bucket<<<NB, B, 0, stream>>>(pairs, basep, x, cnt, row_start, dinv, csr_src,
                                   (__half2*)xs, e, n);

    // layer 1: gather-aggregate xs (16 lanes/node), then fused transform + zs
    const long long n16 = (long long)n * 16;
    k_agg1<<<(int)((n16 + B - 1) / B), B, 0, stream>>>(x, (const __half2*)xs, dinv,
                                                      row_start, cnt, csr_src,
                                                      (float2*)aggX, n);
    k_hidden_z<<<(n + B - 1) / B, B, 0, stream>>>(aggX, W1, b1, W2, dinv, zs, n);

    // layer 2: gather zs (16 lanes/node)
    k_out<<<(int)((n16 + B - 1) / B), B, 0, stream>>>(zs, dinv, row_start, cnt, csr_src, b2, out, n);
}

// Round 17
// 223.530 us; speedup vs baseline: 2.5379x; 1.0156x over previous
//
#include <hip/hip_runtime.h>
#include <hip/hip_fp16.h>

#define IN_F 24
#define HID 64
#define NB 512      // dst buckets (node ranges)
#define NPB 256     // partition blocks (edge slices)
#define GSZ_MAX 256 // max nodes per bucket (ceil(100000/512) = 196)
#define PBUF 7168   // pair capacity per bucket in LDS (mean ~6250, +11 sigma)
#define SRC_BITS 17 // src < 100000 < 2^17; loc < 196 < 2^8

typedef unsigned int u32;

// bucket of node d:  k = floor(d*NB/n)
// node range of bucket b (exact inverse):  [ceil(b*n/NB), ceil((b+1)*n/NB))
__device__ __forceinline__ int bucket_lo(int b, int n) {
    return (int)(((long long)b * n + NB - 1) / NB);
}

// ---------------- pass 1a: per-(slice,bucket) histogram ----------------
__global__ __launch_bounds__(256) void k_pcount(const int* __restrict__ dst,
                                                u32* __restrict__ pc, int e, int n) {
    __shared__ u32 h[NB];
    for (int j = threadIdx.x; j < NB; j += 256) h[j] = 0;
    __syncthreads();
    int blk = blockIdx.x;
    long long begin = (long long)e * blk / NPB;
    long long end   = (long long)e * (blk + 1) / NPB;
    for (long long i = begin + threadIdx.x; i < end; i += 256) {
        int k = (int)((long long)dst[i] * NB / n);
        atomicAdd(&h[k], 1u);
    }
    __syncthreads();
    for (int j = threadIdx.x; j < NB; j += 256) pc[(size_t)blk * NB + j] = h[j];
}

// ---------------- pass 1b-parallel: per-column exclusive scan (NPB=256 rows) ----------------
__global__ __launch_bounds__(256) void k_pscan_a(u32* __restrict__ pc,
                                                 u32* __restrict__ colsum) {
    __shared__ u32 ps[256];
    int t = blockIdx.x;   // column (bucket)
    int tid = threadIdx.x;
    u32 v = pc[(size_t)tid * NB + t];
    ps[tid] = v;
    __syncthreads();
    for (int off = 1; off < 256; off <<= 1) {
        u32 v2 = (tid >= off) ? ps[tid - off] : 0;
        __syncthreads();
        ps[tid] += v2;
        __syncthreads();
    }
    pc[(size_t)tid * NB + t] = ps[tid] - v;   // exclusive within-column
    if (tid == 255) colsum[t] = ps[255];
}

// exclusive scan of the 512 column sums -> bucket bases
__global__ void k_pscan_b(const u32* __restrict__ colsum, u32* __restrict__ basep) {
    __shared__ u32 s[NB];
    int t = threadIdx.x;
    u32 v = colsum[t];
    s[t] = v;
    __syncthreads();
    for (int off = 1; off < NB; off <<= 1) {
        u32 v2 = (t >= off) ? s[t - off] : 0;
        __syncthreads();
        s[t] += v2;
        __syncthreads();
    }
    basep[t] = s[t] - v;
}

// ---------------- pass 1c: direct scatter of packed (loc<<17|src) into bucket order ----------------
// (measured best; staged-LDS variants regressed: R13 53us, R14 62us, vs this <=43us)
__global__ __launch_bounds__(256) void k_part(const int* __restrict__ src,
                                              const int* __restrict__ dst,
                                              const u32* __restrict__ pc,
                                              const u32* __restrict__ basep,
                                              u32* __restrict__ pairs, int e, int n) {
    __shared__ u32 cur[NB];
    int blk = (blockIdx.x & 7) * (NPB / 8) + (blockIdx.x >> 3);  // XCD-affine (perf heuristic)
    for (int j = threadIdx.x; j < NB; j += 256)
        cur[j] = pc[(size_t)blk * NB + j] + basep[j];
    __syncthreads();
    long long begin = (long long)e * blk / NPB;
    long long end   = (long long)e * (blk + 1) / NPB;
    for (long long i = begin + threadIdx.x; i < end; i += 256) {
        int d = dst[i];
        int sv = src[i];
        int k = (int)((long long)d * NB / n);
        u32 loc = (u32)(d - bucket_lo(k, n));
        u32 pos = atomicAdd(&cur[k], 1u);
        pairs[pos] = (loc << SRC_BITS) | (u32)sv;
    }
}

// ---------------- pass 2: per-bucket mini-CSR in LDS (+ fused xs f16 pack) ----------------
__global__ __launch_bounds__(256) void k_bucket(const u32* __restrict__ pairs,
                                                const u32* __restrict__ basep,
                                                const float* __restrict__ x,
                                                int* __restrict__ cnt,
                                                int* __restrict__ row_start,
                                                float* __restrict__ dinv,
                                                int* __restrict__ csr_src,
                                                __half2* __restrict__ xs2, int e, int n) {
    __shared__ u32 pbuf[PBUF];
    __shared__ u32 h[GSZ_MAX];
    __shared__ u32 cur[GSZ_MAX];
    __shared__ u32 sc[GSZ_MAX];
    __shared__ float dloc[GSZ_MAX];
    int b = blockIdx.x;
    int lo = bucket_lo(b, n);
    int hi = bucket_lo(b + 1, n);
    int gsz = hi - lo;               // <= GSZ_MAX
    u32 start = basep[b];
    u32 endp = (b + 1 < NB) ? basep[b + 1] : (u32)e;
    int nbp = (int)(endp - start);
    for (int j = threadIdx.x; j < GSZ_MAX; j += 256) h[j] = 0;
    __syncthreads();
    int stored = nbp < PBUF ? nbp : PBUF;
    for (int i = threadIdx.x; i < stored; i += 256) {
        u32 p = pairs[start + i];
        pbuf[i] = p;
        atomicAdd(&h[p >> SRC_BITS], 1u);
    }
    for (int i = PBUF + threadIdx.x; i < nbp; i += 256) {  // overflow path (rare)
        atomicAdd(&h[pairs[start + i] >> SRC_BITS], 1u);
    }
    __syncthreads();
    int t = threadIdx.x;
    u32 v = h[t];
    sc[t] = v;
    __syncthreads();
    for (int off = 1; off < 256; off <<= 1) {
        u32 v2 = (t >= off) ? sc[t - off] : 0;
        __syncthreads();
        sc[t] += v2;
        __syncthreads();
    }
    u32 excl = sc[t] - v;
    if (t < gsz) {
        float dv = rsqrtf((float)(v + 1));  // +1 self-loop
        cnt[lo + t] = (int)v;
        row_start[lo + t] = (int)(start + excl);
        dinv[lo + t] = dv;
        dloc[t] = dv;
        cur[t] = excl;
    }
    __syncthreads();
    for (int i = threadIdx.x; i < stored; i += 256) {
        u32 p = pbuf[i];
        u32 pos = atomicAdd(&cur[p >> SRC_BITS], 1u);
        csr_src[start + pos] = (int)(p & ((1u << SRC_BITS) - 1));
    }
    for (int i = PBUF + threadIdx.x; i < nbp; i += 256) {
        u32 p = pairs[start + i];
        u32 pos = atomicAdd(&cur[p >> SRC_BITS], 1u);
        csr_src[start + pos] = (int)(p & ((1u << SRC_BITS) - 1));
    }
    // fused pack: xs[i][f] = f16(x[i][f] * dinv[i]) for this bucket's nodes (contiguous)
    const float2* xf = (const float2*)(x + (long long)lo * IN_F);
    for (int i = threadIdx.x; i < gsz * 12; i += 256) {
        float2 vv = xf[i];
        float dn = dloc[i / 12];
        xs2[(long long)lo * 12 + i] = __floats2half2_rn(vv.x * dn, vv.y * dn);
    }
}

// ---------------- fused layer-1 aggregate + transform + layer-2 lin ----------------
// Phase A: 16-lane groups (12 active) gather xs rows, unroll-8 -> sagg LDS.
// Phase B: same 16 lanes transform their node: 4 hidden feats/lane, relu, W2 dot,
//          16-lane shuffle reduce -> zs. W1 LDS reads are wave-broadcast across groups.
__global__ __launch_bounds__(256) void k_agg_hz(const float* __restrict__ x,
                                                const __half2* __restrict__ xs2,
                                                const float* __restrict__ dinv,
                                                const int* __restrict__ row_start,
                                                const int* __restrict__ cnt,
                                                const int* __restrict__ csr_src,
                                                const float* __restrict__ W1,
                                                const float* __restrict__ b1,
                                                const float* __restrict__ W2,
                                                float* __restrict__ zs, int n) {
    __shared__ float w[IN_F * HID];   // k-major: w[k*64+f]
    __shared__ float w2s[HID];
    __shared__ float b1s[HID];
    __shared__ float sagg[16][25];    // 16 nodes x 24 feats (+1 pad)
    for (int j = threadIdx.x; j < IN_F * HID; j += 256) w[j] = W1[j];
    if (threadIdx.x < HID) { w2s[threadIdx.x] = W2[threadIdx.x]; b1s[threadIdx.x] = b1[threadIdx.x]; }
    int g = threadIdx.x >> 4;
    int f2 = threadIdx.x & 15;
    int node = blockIdx.x * 16 + g;
    __syncthreads();
    // ---- Phase A: gather-aggregate (registers), exact k_agg1 structure ----
    if (node < n && f2 < 12) {
        int row = row_start[node];
        int c = cnt[node];
        float ax = 0.0f, ay = 0.0f;
        int j = 0;
        for (; j + 8 <= c; j += 8) {
            const int* cp = csr_src + row + j;
            int s0 = cp[0], s1 = cp[1], s2 = cp[2], s3 = cp[3];
            int s4 = cp[4], s5 = cp[5], s6 = cp[6], s7 = cp[7];
            __half2 h0 = xs2[s0 * 12 + f2];
            __half2 h1 = xs2[s1 * 12 + f2];
            __half2 h2 = xs2[s2 * 12 + f2];
            __half2 h3 = xs2[s3 * 12 + f2];
            __half2 h4 = xs2[s4 * 12 + f2];
            __half2 h5 = xs2[s5 * 12 + f2];
            __half2 h6 = xs2[s6 * 12 + f2];
            __half2 h7 = xs2[s7 * 12 + f2];
            float2 f0 = __half22float2(h0), f1 = __half22float2(h1);
            float2 f2v = __half22float2(h2), f3 = __half22float2(h3);
            float2 f4 = __half22float2(h4), f5 = __half22float2(h5);
            float2 f6 = __half22float2(h6), f7 = __half22float2(h7);
            ax += (f0.x + f1.x) + (f2v.x + f3.x) + ((f4.x + f5.x) + (f6.x + f7.x));
            ay += (f0.y + f1.y) + (f2v.y + f3.y) + ((f4.y + f5.y) + (f6.y + f7.y));
        }
        for (; j < c; ++j) {
            int s = csr_src[row + j];
            float2 fv = __half22float2(xs2[s * 12 + f2]);
            ax += fv.x;
            ay += fv.y;
        }
        float dn = dinv[node];
        float sx = x[(long long)node * IN_F + 2 * f2];
        float sy = x[(long long)node * IN_F + 2 * f2 + 1];
        sagg[g][2 * f2]     = (ax + sx * dn) * dn;
        sagg[g][2 * f2 + 1] = (ay + sy * dn) * dn;
    }
    __syncthreads();
    // ---- Phase B: dense transform, 4 hidden feats per lane ----
    if (node < n) {
        int fb = f2 * 4;
        float h0 = b1s[fb], h1 = b1s[fb + 1], h2 = b1s[fb + 2], h3 = b1s[fb + 3];
#pragma unroll
        for (int k = 0; k < IN_F; ++k) {
            float xv = sagg[g][k];                 // group-uniform -> LDS broadcast
            const float* wr = w + k * HID + fb;
            h0 += xv * wr[0];
            h1 += xv * wr[1];
            h2 += xv * wr[2];
            h3 += xv * wr[3];
        }
        float p = fmaxf(h0, 0.0f) * w2s[fb] + fmaxf(h1, 0.0f) * w2s[fb + 1]
                + fmaxf(h2, 0.0f) * w2s[fb + 2] + fmaxf(h3, 0.0f) * w2s[fb + 3];
        p += __shfl_down(p, 8, 16);
        p += __shfl_down(p, 4, 16);
        p += __shfl_down(p, 2, 16);
        p += __shfl_down(p, 1, 16);
        if (f2 == 0) zs[node] = p * dinv[node];
    }
}

// ---------------- layer 2 gather: 16-lane group per node ----------------
__global__ void k_out(const float* __restrict__ zs, const float* __restrict__ dinv,
                      const int* __restrict__ row_start, const int* __restrict__ cnt,
                      const int* __restrict__ csr_src, const float* __restrict__ b2,
                      float* __restrict__ out, int n) {
    int t = blockIdx.x * blockDim.x + threadIdx.x;
    int node = t >> 4;
    int lane = t & 15;
    if (node >= n) return;
    int row = row_start[node];
    int c = cnt[node];
    float v = 0.0f;
    for (int j = lane; j < c; j += 16) {
        v += zs[csr_src[row + j]];
    }
    v += __shfl_down(v, 8, 16);
    v += __shfl_down(v, 4, 16);
    v += __shfl_down(v, 2, 16);
    v += __shfl_down(v, 1, 16);
    if (lane == 0) {
        out[node] = b2[0] + dinv[node] * (zs[node] + v);
    }
}

extern "C" void kernel_launch(void* const* d_in, const int* in_sizes, int n_in,
                              void* d_out, int out_size, void* d_ws, size_t ws_size,
                              hipStream_t stream) {
    const float* x   = (const float*)d_in[0];
    const int*   ei  = (const int*)d_in[1];
    const float* W1  = (const float*)d_in[2];
    const float* b1  = (const float*)d_in[3];
    const float* W2  = (const float*)d_in[4];
    const float* b2  = (const float*)d_in[5];
    float* out = (float*)d_out;

    const int n = in_sizes[0] / IN_F;      // 100000
    const int e = in_sizes[1] / 2;         // 3200000
    const int* src = ei;
    const int* dst = ei + e;

    const int B = 256;

    // workspace layout. pairs (u32, CSR build) overlays zs (lifetimes disjoint:
    // pairs dead after k_bucket; zs born in k_agg_hz). xs written by k_bucket while
    // other blocks still read pairs -> xs OUTSIDE the overlay. aggX eliminated (fused).
    char* base = (char*)d_ws;
    u32* pairs     = (u32*)base;                        // e u32 (12.8 MB)
    float* zs      = (float*)base;                      // n f32              [overlay]
    size_t ov = ((size_t)e * 4 + 255) & ~(size_t)255;
    char* after    = base + ov;
    int* cnt       = (int*)after;
    int* row_start = cnt + n;
    int* csr_src   = row_start + n;                     // e ints (12.8 MB)
    float* dinv    = (float*)(csr_src + e);
    __half* xs     = (__half*)(dinv + n);               // n*24 f16 (4.8 MB) — NOT overlaid
    u32* pc        = (u32*)(xs + (size_t)n * IN_F);     // NPB*NB u32 (0.5 MB)
    u32* colsum    = pc + (size_t)NPB * NB;             // NB u32
    u32* basep     = colsum + NB;                       // NB u32

    // CSR build: single-read two-level bucket sort (no device-scope atomics)
    k_pcount<<<NPB, B, 0, stream>>>(dst, pc, e, n);
    k_pscan_a<<<NB, B, 0, stream>>>(pc, colsum);
    k_pscan_b<<<1, NB, 0, stream>>>(colsum, basep);
    k_part<<<NPB, B, 0, stream>>>(src, dst, pc, basep, pairs, e, n);
    k_bucket<<<NB, B, 0, stream>>>(pairs, basep, x, cnt, row_start, dinv, csr_src,
                                   (__half2*)xs, e, n);

    // fused layer-1 aggregate + transform (+ layer-2 linear) -> zs
    k_agg_hz<<<(n + 15) / 16, B, 0, stream>>>(x, (const __half2*)xs, dinv,
                                              row_start, cnt, csr_src,
                                              W1, b1, W2, zs, n);

    // layer 2: gather zs (16 lanes/node)
    const long long n16 = (long long)n * 16;
    k_out<<<(int)((n16 + B - 1) / B), B, 0, stream>>>(zs, dinv, row_start, cnt, csr_src, b2, out, n);
}